// Round 3
// baseline (6459.300 us; speedup 1.0000x reference)
//
#include <hip/hip_runtime.h>
#include <stdint.h>

// GlobalAttention fused pipeline, MI355X gfx950.
// Round 2: inputs/outputs are FLOAT32 (per the reference's jnp.float32; the
// bf16 label in the test refers to tolerance mode). Rounds 0-1 read f32 data
// as bf16 -> random exponent-0xFF patterns -> Inf -> softmax NaN.
// Intermediates remain bf16:
//   K1: x(f32)      -> oHalf0  (bf16, first half of d_out)
//   K2: oHalf0      -> oHalf1  (bf16, second half of d_out)
//   K3: oHalf1      -> d_ws    (bf16 bn, 67MB)
//   K4: d_ws        -> d_out   (f32 final, overwrites both halves; no hazard)

#define B_ 2
#define C_ 256
#define H_ 256
#define W_ 256
#define HW_ 65536

typedef unsigned short u16;
typedef unsigned int u32;

__device__ __forceinline__ float b2f(u16 h) {
  union { u32 u; float f; } x; x.u = ((u32)h) << 16; return x.f;
}
__device__ __forceinline__ float b2f_lo(u32 u) {
  union { u32 v; float f; } x; x.v = u << 16; return x.f;
}
__device__ __forceinline__ float b2f_hi(u32 u) {
  union { u32 v; float f; } x; x.v = u & 0xffff0000u; return x.f;
}
__device__ __forceinline__ u16 f2b(float f) {  // RNE
  union { float f; u32 u; } x; x.f = f;
  return (u16)((x.u + 0x7fffu + ((x.u >> 16) & 1u)) >> 16);
}
__device__ __forceinline__ u32 pack2(float a, float b) {
  return (u32)f2b(a) | ((u32)f2b(b) << 16);
}

// ---------------------------------------------------------------------------
// K1: qkv (1x1 conv) + windowed attention. One block per 8x8 window.
// Heads processed in quarters of 4. LDS ~62KB.
// ---------------------------------------------------------------------------
__global__ __launch_bounds__(256) void k_attn(
    const float* __restrict__ x, const float* __restrict__ wqkv,
    const float* __restrict__ rel, u16* __restrict__ o_img)
{
  __shared__ float xs[16][68];    // x chunk: 16 c x 64 pixels (f32)
  __shared__ float wt[16][196];   // w_qkv chunk transposed: 16 c x 192 o (f32)
  __shared__ u16 qk[128][72];     // q rows 0..63, k rows 64..127 (bf16)
  __shared__ u16 vt[64][72];      // v transposed: 64 pixels x 64 dd (bf16)
  __shared__ float sc[64][68];    // scores / probs
  __shared__ float rsum[64];

  const int tid = threadIdx.x;
  const int nb  = blockIdx.x;
  const int b   = nb >> 10;
  const int hh  = (nb >> 5) & 31;
  const int ww  = nb & 31;
  const int h0  = hh << 3, w0 = ww << 3;

  const int pg = tid & 7;    // window row (py)
  const int og = tid >> 3;   // 0..31: owns o_local = og*6 .. og*6+5

  for (int qq = 0; qq < 4; ++qq) {
    // o_local: [0,64)=q, [64,128)=k, [128,192)=v; sub = hl*16+dd, hl in [0,4)
    float acc[6][8];
#pragma unroll
    for (int i = 0; i < 6; ++i)
#pragma unroll
      for (int p = 0; p < 8; ++p) acc[i][p] = 0.f;

    for (int cb = 0; cb < 16; ++cb) {
      const int c0 = cb << 4;
      __syncthreads();
      if (tid < 128) {
        const int cc = tid >> 3, row = tid & 7;
        const float* gp = x + (((size_t)(b * C_ + c0 + cc)) * H_ + (h0 + row)) * W_ + w0;
        *(float4*)&xs[cc][row * 8]     = *(const float4*)gp;
        *(float4*)&xs[cc][row * 8 + 4] = *(const float4*)(gp + 4);
      }
      for (int e = tid; e < 768; e += 256) {
        const int o = e >> 2, q = e & 3;
        const int grow = ((o >> 6) << 8) + (qq << 6) + (o & 63);  // qkv row
        const float4 wv = *(const float4*)&wqkv[(size_t)grow * 256 + c0 + q * 4];
        wt[q * 4 + 0][o] = wv.x;
        wt[q * 4 + 1][o] = wv.y;
        wt[q * 4 + 2][o] = wv.z;
        wt[q * 4 + 3][o] = wv.w;
      }
      __syncthreads();
#pragma unroll 4
      for (int cc = 0; cc < 16; ++cc) {
        const float4 xa = *(const float4*)&xs[cc][pg * 8];
        const float4 xb = *(const float4*)&xs[cc][pg * 8 + 4];
        const float xf[8] = {xa.x, xa.y, xa.z, xa.w, xb.x, xb.y, xb.z, xb.w};
        const float2 wa = *(const float2*)&wt[cc][og * 6];
        const float2 wb = *(const float2*)&wt[cc][og * 6 + 2];
        const float2 wc = *(const float2*)&wt[cc][og * 6 + 4];
        const float wf[6] = {wa.x, wa.y, wb.x, wb.y, wc.x, wc.y};
#pragma unroll
        for (int i = 0; i < 6; ++i)
#pragma unroll
          for (int p = 0; p < 8; ++p) acc[i][p] += wf[i] * xf[p];
      }
    }
    __syncthreads();
#pragma unroll
    for (int i = 0; i < 6; ++i) {
      const int ol = og * 6 + i;
      if (ol < 128) {
        uint4 uv;
        uv.x = pack2(acc[i][0], acc[i][1]);
        uv.y = pack2(acc[i][2], acc[i][3]);
        uv.z = pack2(acc[i][4], acc[i][5]);
        uv.w = pack2(acc[i][6], acc[i][7]);
        *(uint4*)&qk[ol][pg * 8] = uv;
      } else {
        const int col = ol - 128;
#pragma unroll
        for (int p = 0; p < 8; ++p) vt[pg * 8 + p][col] = f2b(acc[i][p]);
      }
    }
    __syncthreads();

    for (int hl = 0; hl < 4; ++hl) {
      const int head = (qq << 2) + hl;
      {  // dots = 0.25*q.k^T + bias  -> sc (fp32)
        const int ti = tid >> 4, tj = tid & 15;
        const int i0 = ti * 4, j0 = tj * 4;
        float dd_[4][4];
#pragma unroll
        for (int a = 0; a < 4; ++a)
#pragma unroll
          for (int bb = 0; bb < 4; ++bb) dd_[a][bb] = 0.f;
#pragma unroll
        for (int dd = 0; dd < 16; ++dd) {
          const int qrow = hl * 16 + dd;
          const uint2 qv = *(const uint2*)&qk[qrow][i0];
          const uint2 kv = *(const uint2*)&qk[64 + qrow][j0];
          const float fq[4] = {b2f_lo(qv.x), b2f_hi(qv.x), b2f_lo(qv.y), b2f_hi(qv.y)};
          const float fk[4] = {b2f_lo(kv.x), b2f_hi(kv.x), b2f_lo(kv.y), b2f_hi(kv.y)};
#pragma unroll
          for (int a = 0; a < 4; ++a)
#pragma unroll
            for (int bb = 0; bb < 4; ++bb) dd_[a][bb] += fq[a] * fk[bb];
        }
#pragma unroll
        for (int a = 0; a < 4; ++a) {
          const int i = i0 + a, iy = i >> 3, ix = i & 7;
          float t4[4];
#pragma unroll
          for (int bb = 0; bb < 4; ++bb) {
            const int j = j0 + bb, jy = j >> 3, jx = j & 7;
            const int ridx = (iy - jy + 7) * 15 + (ix - jx + 7);
            t4[bb] = dd_[a][bb] * 0.25f + rel[ridx * 16 + head];
          }
          float4 sv; sv.x = t4[0]; sv.y = t4[1]; sv.z = t4[2]; sv.w = t4[3];
          *(float4*)&sc[i][j0] = sv;
        }
      }
      __syncthreads();
      if (tid < 64) {  // row softmax (unnormalized exp; 1/sum in rsum)
        float m = -1e30f;
        for (int j = 0; j < 64; j += 4) {
          const float4 v = *(const float4*)&sc[tid][j];
          m = fmaxf(m, fmaxf(fmaxf(v.x, v.y), fmaxf(v.z, v.w)));
        }
        float s = 0.f;
        for (int j = 0; j < 64; j += 4) {
          float4 v = *(float4*)&sc[tid][j];
          v.x = __expf(v.x - m); v.y = __expf(v.y - m);
          v.z = __expf(v.z - m); v.w = __expf(v.w - m);
          s += v.x + v.y + v.z + v.w;
          *(float4*)&sc[tid][j] = v;
        }
        rsum[tid] = 1.0f / s;
      }
      __syncthreads();
      {  // o = (P @ V) * rsum ; write to global (bf16 intermediate)
        const int i = tid >> 2, dg = tid & 3;
        float a0 = 0.f, a1 = 0.f, a2 = 0.f, a3 = 0.f;
        for (int j = 0; j < 64; ++j) {
          const float p = sc[i][j];
          const uint2 vv = *(const uint2*)&vt[j][hl * 16 + dg * 4];
          a0 += p * b2f_lo(vv.x);
          a1 += p * b2f_hi(vv.x);
          a2 += p * b2f_lo(vv.y);
          a3 += p * b2f_hi(vv.y);
        }
        const float r = rsum[i];
        const int ch = head * 16 + dg * 4;
        const int iy = i >> 3, ix = i & 7;
        u16* op = o_img + (((size_t)(b * C_ + ch)) * H_ + (h0 + iy)) * W_ + (w0 + ix);
        op[0]                 = f2b(a0 * r);
        op[(size_t)HW_]       = f2b(a1 * r);
        op[(size_t)2 * HW_]   = f2b(a2 * r);
        op[(size_t)3 * HW_]   = f2b(a3 * r);
      }
      __syncthreads();
    }
  }
}

// ---------------------------------------------------------------------------
// K2: out1 = ox + oy + bx + by.  8-tap cross-channel convs (kernel (8,1) and
// (1,8)), input o reflect-padded by (0,1) then zero pad 3 (virtual 257 grid:
// idx 256 -> 254, outside -> 0).  Block: 64 o x 64 w at one (b,h).
// ---------------------------------------------------------------------------
__global__ __launch_bounds__(256) void k_conv2(
    const u16* __restrict__ oin, const float* __restrict__ wxg, const float* __restrict__ wyg,
    const float* __restrict__ bxg, const float* __restrict__ byg, u16* __restrict__ out1)
{
  __shared__ u16 inx[8][8][68];   // [c][t][w0..w0+63]  rows h-3+t (bf16)
  __shared__ u16 iny[8][72];      // [c][w0-3 .. w0+68] row h (bf16)
  __shared__ float wxl[8][8][68]; // [c][t][o] (f32)
  __shared__ float wyl[8][8][68];

  const int tid = threadIdx.x, nb = blockIdx.x;
  const int wtile = nb & 3, og = (nb >> 2) & 3, h = (nb >> 4) & 255, b = nb >> 12;
  const int w0 = wtile * 64;
  const int tog = tid >> 4, twg = tid & 15;  // o = og*64+tog*4+a ; w = w0+twg*4+s

  float acc[4][4];
#pragma unroll
  for (int a = 0; a < 4; ++a) {
    const int o = og * 64 + tog * 4 + a;
    const float bias = bxg[o] + byg[o];
#pragma unroll
    for (int s = 0; s < 4; ++s) acc[a][s] = bias;
  }

  for (int cb = 0; cb < 32; ++cb) {
    const int c0 = cb * 8;
    __syncthreads();
#pragma unroll
    for (int k = 0; k < 4; ++k) {
      const int e = tid + k * 256;
      const int cc = e >> 7, t = (e >> 4) & 7, seg = e & 15;
      const int r = h - 3 + t;
      uint2 val; val.x = 0u; val.y = 0u;
      if (r >= 0 && r <= 256) {
        const int rr = (r == 256) ? 254 : r;
        val = *(const uint2*)&oin[(((size_t)(b * C_ + c0 + cc)) * H_ + rr) * W_ + w0 + seg * 4];
      }
      *(uint2*)&inx[cc][t][seg * 4] = val;
    }
    for (int e = tid; e < 576; e += 256) {
      const int cc = e / 72, cl = e % 72;
      const int cg = w0 - 3 + cl;
      u16 v = 0;
      if (cg >= 0 && cg <= 256) {
        const int cgm = (cg == 256) ? 254 : cg;
        v = oin[(((size_t)(b * C_ + c0 + cc)) * H_ + h) * W_ + cgm];
      }
      iny[cc][cl] = v;
    }
#pragma unroll
    for (int k = 0; k < 2; ++k) {
      const int e2 = tid + k * 256;
      const int o = e2 >> 3, q8 = e2 & 7;
      const size_t wbase = ((size_t)(og * 64 + o)) * 2048 + (size_t)(c0 + q8) * 8;
      const float4 wa = *(const float4*)&wxg[wbase];
      const float4 wb = *(const float4*)&wxg[wbase + 4];
      wxl[q8][0][o] = wa.x; wxl[q8][1][o] = wa.y; wxl[q8][2][o] = wa.z; wxl[q8][3][o] = wa.w;
      wxl[q8][4][o] = wb.x; wxl[q8][5][o] = wb.y; wxl[q8][6][o] = wb.z; wxl[q8][7][o] = wb.w;
      const float4 ya = *(const float4*)&wyg[wbase];
      const float4 yb = *(const float4*)&wyg[wbase + 4];
      wyl[q8][0][o] = ya.x; wyl[q8][1][o] = ya.y; wyl[q8][2][o] = ya.z; wyl[q8][3][o] = ya.w;
      wyl[q8][4][o] = yb.x; wyl[q8][5][o] = yb.y; wyl[q8][6][o] = yb.z; wyl[q8][7][o] = yb.w;
    }
    __syncthreads();
    for (int cc = 0; cc < 8; ++cc) {
      const uint2 fa = *(const uint2*)&iny[cc][twg * 4];
      const uint2 fb = *(const uint2*)&iny[cc][twg * 4 + 4];
      const uint2 fc = *(const uint2*)&iny[cc][twg * 4 + 8];
      float fy[12];
      fy[0] = b2f_lo(fa.x); fy[1] = b2f_hi(fa.x); fy[2] = b2f_lo(fa.y); fy[3] = b2f_hi(fa.y);
      fy[4] = b2f_lo(fb.x); fy[5] = b2f_hi(fb.x); fy[6] = b2f_lo(fb.y); fy[7] = b2f_hi(fb.y);
      fy[8] = b2f_lo(fc.x); fy[9] = b2f_hi(fc.x); fy[10] = b2f_lo(fc.y); fy[11] = b2f_hi(fc.y);
#pragma unroll
      for (int t = 0; t < 8; ++t) {
        const uint2 xi = *(const uint2*)&inx[cc][t][twg * 4];
        const float4 wxa = *(const float4*)&wxl[cc][t][tog * 4];
        const float4 wya = *(const float4*)&wyl[cc][t][tog * 4];
        const float fx[4]  = {b2f_lo(xi.x), b2f_hi(xi.x), b2f_lo(xi.y), b2f_hi(xi.y)};
        const float wxf[4] = {wxa.x, wxa.y, wxa.z, wxa.w};
        const float wyf[4] = {wya.x, wya.y, wya.z, wya.w};
#pragma unroll
        for (int a = 0; a < 4; ++a)
#pragma unroll
          for (int s = 0; s < 4; ++s)
            acc[a][s] += wxf[a] * fx[s] + wyf[a] * fy[t + s];
      }
    }
  }
#pragma unroll
  for (int a = 0; a < 4; ++a) {
    const int o = og * 64 + tog * 4 + a;
    uint2 uv;
    uv.x = pack2(acc[a][0], acc[a][1]);
    uv.y = pack2(acc[a][2], acc[a][3]);
    *(uint2*)&out1[(((size_t)(b * C_ + o)) * H_ + h) * W_ + w0 + twg * 4] = uv;
  }
}

// ---------------------------------------------------------------------------
// K3: depthwise 8x8 conv (on reflect(0,1)x(0,1)-padded out1, zero pad 3) + BN.
// Block: one (b, c, 16-row tile), full width.
// ---------------------------------------------------------------------------
__global__ __launch_bounds__(256) void k_dwbn(
    const u16* __restrict__ out1, const float* __restrict__ wdw,
    const float* __restrict__ gam, const float* __restrict__ bet,
    const float* __restrict__ mea, const float* __restrict__ var,
    u16* __restrict__ bno)
{
  __shared__ u16 tile[23][264];
  const int tid = threadIdx.x, nb = blockIdx.x;
  const int c = nb & 255, ht = (nb >> 8) & 15, b = nb >> 12;
  const int h0 = ht * 16;

  for (int e = tid; e < 23 * 264; e += 256) {
    const int tr = e / 264, tc = e % 264;
    const int r = h0 - 3 + tr;
    const int cg = tc - 3;
    u16 v = 0;
    if (r >= 0 && r <= 256 && cg >= 0 && cg <= 256) {
      const int rr = (r == 256) ? 254 : r;
      const int cgm = (cg == 256) ? 254 : cg;
      v = out1[(((size_t)(b * C_ + c)) * H_ + rr) * W_ + cgm];
    }
    tile[tr][tc] = v;
  }
  float wk[64];
#pragma unroll
  for (int k2 = 0; k2 < 64; ++k2) wk[k2] = wdw[c * 64 + k2];
  const float scl = gam[c] / sqrtf(var[c] + 1e-5f);
  const float shf = bet[c] - mea[c] * scl;
  __syncthreads();

  const int wg = tid & 31, hg = tid >> 5;
  const int w0 = wg * 8;
#pragma unroll
  for (int k = 0; k < 2; ++k) {
    const int hl = hg * 2 + k;
    float a[8];
#pragma unroll
    for (int s = 0; s < 8; ++s) a[s] = 0.f;
#pragma unroll
    for (int i = 0; i < 8; ++i) {
      const uint4 va = *(const uint4*)&tile[hl + i][w0];
      const uint4 vb = *(const uint4*)&tile[hl + i][w0 + 8];
      float f[16];
      f[0] = b2f_lo(va.x);  f[1] = b2f_hi(va.x);  f[2] = b2f_lo(va.y);  f[3] = b2f_hi(va.y);
      f[4] = b2f_lo(va.z);  f[5] = b2f_hi(va.z);  f[6] = b2f_lo(va.w);  f[7] = b2f_hi(va.w);
      f[8] = b2f_lo(vb.x);  f[9] = b2f_hi(vb.x);  f[10] = b2f_lo(vb.y); f[11] = b2f_hi(vb.y);
      f[12] = b2f_lo(vb.z); f[13] = b2f_hi(vb.z); f[14] = b2f_lo(vb.w); f[15] = b2f_hi(vb.w);
#pragma unroll
      for (int j = 0; j < 8; ++j) {
        const float wv = wk[i * 8 + j];
#pragma unroll
        for (int s = 0; s < 8; ++s) a[s] += f[s + j] * wv;
      }
    }
    uint4 uv;
    uv.x = pack2(a[0] * scl + shf, a[1] * scl + shf);
    uv.y = pack2(a[2] * scl + shf, a[3] * scl + shf);
    uv.z = pack2(a[4] * scl + shf, a[5] * scl + shf);
    uv.w = pack2(a[6] * scl + shf, a[7] * scl + shf);
    *(uint4*)&bno[(((size_t)(b * C_ + c)) * H_ + h0 + hl) * W_ + w0] = uv;
  }
}

// ---------------------------------------------------------------------------
// K4: 1x1 projection: out[b,o,h,w] = sum_c bn[b,c,h,w] * w_proj[o,c]
// Block: 256 o x 64 w at one (b,h). Output FLOAT32.
// ---------------------------------------------------------------------------
__global__ __launch_bounds__(256) void k_proj(
    const u16* __restrict__ bno, const float* __restrict__ wp, float* __restrict__ out)
{
  __shared__ u16 bn[256][72];
  __shared__ u16 wpT[32][264];
  const int tid = threadIdx.x, nb = blockIdx.x;
  const int wtile = nb & 3, h = (nb >> 2) & 255, b = nb >> 10;
  const int w0 = wtile * 64;
  const int og = tid >> 3, pg = tid & 7;  // o = og*8+a, w = w0+pg*8+s

  for (int k = 0; k < 8; ++k) {
    const int e = tid + k * 256;
    const int cc2 = e >> 3, seg = e & 7;
    *(uint4*)&bn[cc2][seg * 8] =
        *(const uint4*)&bno[(((size_t)(b * C_ + cc2)) * H_ + h) * W_ + w0 + seg * 8];
  }
  float acc[8][8];
#pragma unroll
  for (int a = 0; a < 8; ++a)
#pragma unroll
    for (int s = 0; s < 8; ++s) acc[a][s] = 0.f;

  for (int cb = 0; cb < 8; ++cb) {
    const int c0 = cb * 32;
    __syncthreads();
#pragma unroll
    for (int k = 0; k < 8; ++k) {
      const int e = tid + k * 256;
      const int o = e >> 3, g = e & 7;
      const float4 wv = *(const float4*)&wp[(size_t)o * 256 + c0 + g * 4];
      wpT[g * 4 + 0][o] = f2b(wv.x);
      wpT[g * 4 + 1][o] = f2b(wv.y);
      wpT[g * 4 + 2][o] = f2b(wv.z);
      wpT[g * 4 + 3][o] = f2b(wv.w);
    }
    __syncthreads();
    for (int cc = 0; cc < 32; ++cc) {
      const uint4 bv = *(const uint4*)&bn[c0 + cc][pg * 8];
      float bf[8];
      bf[0] = b2f_lo(bv.x); bf[1] = b2f_hi(bv.x); bf[2] = b2f_lo(bv.y); bf[3] = b2f_hi(bv.y);
      bf[4] = b2f_lo(bv.z); bf[5] = b2f_hi(bv.z); bf[6] = b2f_lo(bv.w); bf[7] = b2f_hi(bv.w);
      const uint4 wv = *(const uint4*)&wpT[cc][og * 8];
      float wf[8];
      wf[0] = b2f_lo(wv.x); wf[1] = b2f_hi(wv.x); wf[2] = b2f_lo(wv.y); wf[3] = b2f_hi(wv.y);
      wf[4] = b2f_lo(wv.z); wf[5] = b2f_hi(wv.z); wf[6] = b2f_lo(wv.w); wf[7] = b2f_hi(wv.w);
#pragma unroll
      for (int a = 0; a < 8; ++a)
#pragma unroll
        for (int s = 0; s < 8; ++s) acc[a][s] += wf[a] * bf[s];
    }
  }
#pragma unroll
  for (int a = 0; a < 8; ++a) {
    const int o = og * 8 + a;
    float* op = out + (((size_t)(b * C_ + o)) * H_ + h) * W_ + w0 + pg * 8;
    float4 v0; v0.x = acc[a][0]; v0.y = acc[a][1]; v0.z = acc[a][2]; v0.w = acc[a][3];
    float4 v1; v1.x = acc[a][4]; v1.y = acc[a][5]; v1.z = acc[a][6]; v1.w = acc[a][7];
    *(float4*)op = v0;
    *(float4*)(op + 4) = v1;
  }
}

// ---------------------------------------------------------------------------
extern "C" void kernel_launch(void* const* d_in, const int* in_sizes, int n_in,
                              void* d_out, int out_size, void* d_ws, size_t ws_size,
                              hipStream_t stream)
{
  const float* x     = (const float*)d_in[0];
  const float* wqkv  = (const float*)d_in[1];
  const float* rel   = (const float*)d_in[2];
  const float* wax   = (const float*)d_in[3];
  const float* bax   = (const float*)d_in[4];
  const float* way   = (const float*)d_in[5];
  const float* bay   = (const float*)d_in[6];
  const float* wdw   = (const float*)d_in[7];
  const float* gam   = (const float*)d_in[8];
  const float* bet   = (const float*)d_in[9];
  const float* mea   = (const float*)d_in[10];
  const float* var   = (const float*)d_in[11];
  const float* wproj = (const float*)d_in[12];
  float* out = (float*)d_out;

  const size_t N = (size_t)B_ * C_ * H_ * W_;   // 33.5M elements
  u16* oHalf0 = (u16*)d_out;        // bf16 o (first 67MB of f32 out buffer)
  u16* oHalf1 = (u16*)d_out + N;    // bf16 out1 (second 67MB)
  u16* bnbuf  = (u16*)d_ws;         // bf16 bn (67MB of workspace)

  hipLaunchKernelGGL(k_attn,  dim3(2048), dim3(256), 0, stream, x, wqkv, rel, oHalf0);
  hipLaunchKernelGGL(k_conv2, dim3(8192), dim3(256), 0, stream, oHalf0, wax, way, bax, bay, oHalf1);
  hipLaunchKernelGGL(k_dwbn,  dim3(8192), dim3(256), 0, stream, oHalf1, wdw, gam, bet, mea, var, bnbuf);
  hipLaunchKernelGGL(k_proj,  dim3(2048), dim3(256), 0, stream, bnbuf, wproj, out);
}

// Round 4
// 2314.246 us; speedup vs baseline: 2.7911x; 2.7911x over previous
//
#include <hip/hip_runtime.h>
#include <stdint.h>

// GlobalAttention fused pipeline, MI355X gfx950.
// Round 4: K2 (the 274-GFLOP dual 8-tap conv, 93% of runtime) moved to MFMA
// (v_mfma_f32_32x32x16_bf16). K1 now emits o in NHWC so the image B-operand
// is channel-contiguous; K0 pre-transposes conv weights to [conv][t][o][c].
//   K0: wx,wy (f32) -> WT bf16 [2][8][256][256] @ d_ws[0..2MB)
//   K1: x(f32)      -> o NHWC bf16 (first half of d_out arena)
//   K2: o,WT        -> out1 NCHW bf16 (second half of d_out arena)  [MFMA]
//   K3: out1        -> bn NCHW bf16 @ d_ws (overwrites dead WT)
//   K4: bn          -> d_out f32 final

#define B_ 2
#define C_ 256
#define H_ 256
#define W_ 256
#define HW_ 65536

typedef unsigned short u16;
typedef unsigned int u32;
typedef short bf16x8 __attribute__((ext_vector_type(8)));
typedef float f32x16 __attribute__((ext_vector_type(16)));

__device__ __forceinline__ float b2f(u16 h) {
  union { u32 u; float f; } x; x.u = ((u32)h) << 16; return x.f;
}
__device__ __forceinline__ float b2f_lo(u32 u) {
  union { u32 v; float f; } x; x.v = u << 16; return x.f;
}
__device__ __forceinline__ float b2f_hi(u32 u) {
  union { u32 v; float f; } x; x.v = u & 0xffff0000u; return x.f;
}
__device__ __forceinline__ u16 f2b(float f) {  // RNE
  union { float f; u32 u; } x; x.f = f;
  return (u16)((x.u + 0x7fffu + ((x.u >> 16) & 1u)) >> 16);
}
__device__ __forceinline__ u32 pack2(float a, float b) {
  return (u32)f2b(a) | ((u32)f2b(b) << 16);
}

// ---------------------------------------------------------------------------
// K0: weight transpose  wx/wy [o][c][t] f32  ->  WT bf16 [conv][t][o][c]
// ---------------------------------------------------------------------------
__global__ __launch_bounds__(256) void k_wt(
    const float* __restrict__ wx, const float* __restrict__ wy,
    u16* __restrict__ wt)
{
  const int o = blockIdx.x, c = threadIdx.x;
  const float* px = wx + ((size_t)o * 256 + c) * 8;
  const float* py = wy + ((size_t)o * 256 + c) * 8;
#pragma unroll
  for (int t = 0; t < 8; ++t) {
    wt[(size_t)t * 65536 + o * 256 + c]          = f2b(px[t]);
    wt[524288 + (size_t)t * 65536 + o * 256 + c] = f2b(py[t]);
  }
}

// ---------------------------------------------------------------------------
// K1: qkv (1x1 conv) + windowed attention. One block per 8x8 window.
// Output o written NHWC bf16: o[b][h][w][c].
// ---------------------------------------------------------------------------
__global__ __launch_bounds__(256) void k_attn(
    const float* __restrict__ x, const float* __restrict__ wqkv,
    const float* __restrict__ rel, u16* __restrict__ o_img)
{
  __shared__ float xs[16][68];
  __shared__ float wt[16][196];
  __shared__ u16 qk[128][72];
  __shared__ u16 vt[64][72];
  __shared__ float sc[64][68];
  __shared__ float rsum[64];

  const int tid = threadIdx.x;
  const int nb  = blockIdx.x;
  const int b   = nb >> 10;
  const int hh  = (nb >> 5) & 31;
  const int ww  = nb & 31;
  const int h0  = hh << 3, w0 = ww << 3;

  const int pg = tid & 7;
  const int og = tid >> 3;

  for (int qq = 0; qq < 4; ++qq) {
    float acc[6][8];
#pragma unroll
    for (int i = 0; i < 6; ++i)
#pragma unroll
      for (int p = 0; p < 8; ++p) acc[i][p] = 0.f;

    for (int cb = 0; cb < 16; ++cb) {
      const int c0 = cb << 4;
      __syncthreads();
      if (tid < 128) {
        const int cc = tid >> 3, row = tid & 7;
        const float* gp = x + (((size_t)(b * C_ + c0 + cc)) * H_ + (h0 + row)) * W_ + w0;
        *(float4*)&xs[cc][row * 8]     = *(const float4*)gp;
        *(float4*)&xs[cc][row * 8 + 4] = *(const float4*)(gp + 4);
      }
      for (int e = tid; e < 768; e += 256) {
        const int o = e >> 2, q = e & 3;
        const int grow = ((o >> 6) << 8) + (qq << 6) + (o & 63);
        const float4 wv = *(const float4*)&wqkv[(size_t)grow * 256 + c0 + q * 4];
        wt[q * 4 + 0][o] = wv.x;
        wt[q * 4 + 1][o] = wv.y;
        wt[q * 4 + 2][o] = wv.z;
        wt[q * 4 + 3][o] = wv.w;
      }
      __syncthreads();
#pragma unroll 4
      for (int cc = 0; cc < 16; ++cc) {
        const float4 xa = *(const float4*)&xs[cc][pg * 8];
        const float4 xb = *(const float4*)&xs[cc][pg * 8 + 4];
        const float xf[8] = {xa.x, xa.y, xa.z, xa.w, xb.x, xb.y, xb.z, xb.w};
        const float2 wa = *(const float2*)&wt[cc][og * 6];
        const float2 wb = *(const float2*)&wt[cc][og * 6 + 2];
        const float2 wc = *(const float2*)&wt[cc][og * 6 + 4];
        const float wf[6] = {wa.x, wa.y, wb.x, wb.y, wc.x, wc.y};
#pragma unroll
        for (int i = 0; i < 6; ++i)
#pragma unroll
          for (int p = 0; p < 8; ++p) acc[i][p] += wf[i] * xf[p];
      }
    }
    __syncthreads();
#pragma unroll
    for (int i = 0; i < 6; ++i) {
      const int ol = og * 6 + i;
      if (ol < 128) {
        uint4 uv;
        uv.x = pack2(acc[i][0], acc[i][1]);
        uv.y = pack2(acc[i][2], acc[i][3]);
        uv.z = pack2(acc[i][4], acc[i][5]);
        uv.w = pack2(acc[i][6], acc[i][7]);
        *(uint4*)&qk[ol][pg * 8] = uv;
      } else {
        const int col = ol - 128;
#pragma unroll
        for (int p = 0; p < 8; ++p) vt[pg * 8 + p][col] = f2b(acc[i][p]);
      }
    }
    __syncthreads();

    for (int hl = 0; hl < 4; ++hl) {
      const int head = (qq << 2) + hl;
      {
        const int ti = tid >> 4, tj = tid & 15;
        const int i0 = ti * 4, j0 = tj * 4;
        float dd_[4][4];
#pragma unroll
        for (int a = 0; a < 4; ++a)
#pragma unroll
          for (int bb = 0; bb < 4; ++bb) dd_[a][bb] = 0.f;
#pragma unroll
        for (int dd = 0; dd < 16; ++dd) {
          const int qrow = hl * 16 + dd;
          const uint2 qv = *(const uint2*)&qk[qrow][i0];
          const uint2 kv = *(const uint2*)&qk[64 + qrow][j0];
          const float fq[4] = {b2f_lo(qv.x), b2f_hi(qv.x), b2f_lo(qv.y), b2f_hi(qv.y)};
          const float fk[4] = {b2f_lo(kv.x), b2f_hi(kv.x), b2f_lo(kv.y), b2f_hi(kv.y)};
#pragma unroll
          for (int a = 0; a < 4; ++a)
#pragma unroll
            for (int bb = 0; bb < 4; ++bb) dd_[a][bb] += fq[a] * fk[bb];
        }
#pragma unroll
        for (int a = 0; a < 4; ++a) {
          const int i = i0 + a, iy = i >> 3, ix = i & 7;
          float t4[4];
#pragma unroll
          for (int bb = 0; bb < 4; ++bb) {
            const int j = j0 + bb, jy = j >> 3, jx = j & 7;
            const int ridx = (iy - jy + 7) * 15 + (ix - jx + 7);
            t4[bb] = dd_[a][bb] * 0.25f + rel[ridx * 16 + head];
          }
          float4 sv; sv.x = t4[0]; sv.y = t4[1]; sv.z = t4[2]; sv.w = t4[3];
          *(float4*)&sc[i][j0] = sv;
        }
      }
      __syncthreads();
      if (tid < 64) {
        float m = -1e30f;
        for (int j = 0; j < 64; j += 4) {
          const float4 v = *(const float4*)&sc[tid][j];
          m = fmaxf(m, fmaxf(fmaxf(v.x, v.y), fmaxf(v.z, v.w)));
        }
        float s = 0.f;
        for (int j = 0; j < 64; j += 4) {
          float4 v = *(float4*)&sc[tid][j];
          v.x = __expf(v.x - m); v.y = __expf(v.y - m);
          v.z = __expf(v.z - m); v.w = __expf(v.w - m);
          s += v.x + v.y + v.z + v.w;
          *(float4*)&sc[tid][j] = v;
        }
        rsum[tid] = 1.0f / s;
      }
      __syncthreads();
      {
        const int i = tid >> 2, dg = tid & 3;
        float a0 = 0.f, a1 = 0.f, a2 = 0.f, a3 = 0.f;
        for (int j = 0; j < 64; ++j) {
          const float p = sc[i][j];
          const uint2 vv = *(const uint2*)&vt[j][hl * 16 + dg * 4];
          a0 += p * b2f_lo(vv.x);
          a1 += p * b2f_hi(vv.x);
          a2 += p * b2f_lo(vv.y);
          a3 += p * b2f_hi(vv.y);
        }
        const float r = rsum[i];
        const int ch = head * 16 + dg * 4;
        const int iy = i >> 3, ix = i & 7;
        // NHWC write: o[b][h][w][c], 4 consecutive channels
        u16* op = o_img + (((size_t)(b * H_ + h0 + iy)) * W_ + (w0 + ix)) * C_ + ch;
        *(u32*)op       = pack2(a0 * r, a1 * r);
        *(u32*)(op + 2) = pack2(a2 * r, a3 * r);
      }
      __syncthreads();
    }
  }
}

// ---------------------------------------------------------------------------
// K2 (MFMA): out1 = ox + oy + bx + by.
// Block = 128 o x 128 w at one (b,h); 4 waves of 64x64 (2x2 mfma 32x32x16).
// Image staged NHWC -> LDS tile[8 rows][136 w][16 c (pad 20)] per 16-c chunk.
// A-frags (weights) loaded straight from global WT[conv][t][o][c] (L2-hot).
// ---------------------------------------------------------------------------
__global__ __launch_bounds__(256) void k_conv2m(
    const u16* __restrict__ o_nhwc, const u16* __restrict__ wt,
    const float* __restrict__ bxg, const float* __restrict__ byg,
    u16* __restrict__ out1)
{
  __shared__ u16 tile[8 * 136 * 20];   // 43.5 KB
  __shared__ float bias_l[128];

  const int tid = threadIdx.x, nb = blockIdx.x;
  const int wh = nb & 1, oh = (nb >> 1) & 1, h = (nb >> 2) & 255, b = nb >> 10;
  const int ob = oh * 128, wb0 = wh * 128;
  const int lane = tid & 63, wid = tid >> 6;
  const int wo = (wid >> 1) * 64, wwv = (wid & 1) * 64;
  const int n = lane & 31, h5 = lane >> 5;

  if (tid < 128) bias_l[tid] = bxg[ob + tid] + byg[ob + tid];

  f32x16 acc[2][2];
#pragma unroll
  for (int mt = 0; mt < 2; ++mt)
#pragma unroll
    for (int nt = 0; nt < 2; ++nt)
#pragma unroll
      for (int i = 0; i < 16; ++i) acc[mt][nt][i] = 0.f;

  for (int cb = 0; cb < 16; ++cb) {
    const int c0 = cb * 16;
    __syncthreads();
    // ---- stage 8 rows x 136 w x 16 c (NHWC source: 32B contiguous) ----
    for (int e = tid; e < 1088; e += 256) {
      const int r = e / 136, wi = e - r * 136;
      const int hp = h - 3 + r;
      const int wp = wb0 + wi - 4;
      uint2 v0 = make_uint2(0, 0), v1 = v0, v2 = v0, v3 = v0;
      if (hp >= 0 && hp <= 256 && wp >= 0 && wp <= 256) {
        const int hr = (hp == 256) ? 254 : hp;
        const int wr = (wp == 256) ? 254 : wp;
        const u16* src = o_nhwc + (((size_t)(b * H_ + hr)) * W_ + wr) * C_ + c0;
        const uint4 A  = *(const uint4*)src;
        const uint4 Bv = *(const uint4*)(src + 8);
        v0 = make_uint2(A.x, A.y);  v1 = make_uint2(A.z, A.w);
        v2 = make_uint2(Bv.x, Bv.y); v3 = make_uint2(Bv.z, Bv.w);
      }
      u16* d = &tile[(r * 136 + wi) * 20];
      *(uint2*)(d)      = v0;
      *(uint2*)(d + 4)  = v1;
      *(uint2*)(d + 8)  = v2;
      *(uint2*)(d + 12) = v3;
    }
    __syncthreads();
    // ---- compute: 2 convs x 8 taps, K=16 channels each ----
#pragma unroll
    for (int cv = 0; cv < 2; ++cv) {
      const u16* wbase = wt + (size_t)cv * 524288;
#pragma unroll
      for (int t = 0; t < 8; ++t) {
        bf16x8 a[2], bb[2];
#pragma unroll
        for (int mt = 0; mt < 2; ++mt) {
          const int o = ob + wo + mt * 32 + n;
          union { uint4 u; bf16x8 v; } U;
          U.u = *(const uint4*)(wbase + ((size_t)(t * 256 + o)) * 256 + c0 + h5 * 8);
          a[mt] = U.v;
        }
#pragma unroll
        for (int nt = 0; nt < 2; ++nt) {
          const int rr = cv ? 3 : t;
          const int wi = wwv + nt * 32 + n + (cv ? (t + 1) : 4);
          const u16* p = &tile[(rr * 136 + wi) * 20 + h5 * 8];
          union { uint2 u[2]; bf16x8 v; } U;
          U.u[0] = *(const uint2*)p;
          U.u[1] = *(const uint2*)(p + 4);
          bb[nt] = U.v;
        }
        acc[0][0] = __builtin_amdgcn_mfma_f32_32x32x16_bf16(a[0], bb[0], acc[0][0], 0, 0, 0);
        acc[0][1] = __builtin_amdgcn_mfma_f32_32x32x16_bf16(a[0], bb[1], acc[0][1], 0, 0, 0);
        acc[1][0] = __builtin_amdgcn_mfma_f32_32x32x16_bf16(a[1], bb[0], acc[1][0], 0, 0, 0);
        acc[1][1] = __builtin_amdgcn_mfma_f32_32x32x16_bf16(a[1], bb[1], acc[1][1], 0, 0, 0);
      }
    }
  }
  // ---- epilogue: +bias, bf16, NCHW ----
#pragma unroll
  for (int mt = 0; mt < 2; ++mt)
#pragma unroll
    for (int nt = 0; nt < 2; ++nt)
#pragma unroll
      for (int r = 0; r < 16; ++r) {
        const int om = wo + mt * 32 + (r & 3) + 8 * (r >> 2) + 4 * h5;
        const int o = ob + om;
        const int wg = wb0 + wwv + nt * 32 + n;
        const float v = acc[mt][nt][r] + bias_l[om];
        out1[(((size_t)(b * C_ + o)) * H_ + h) * W_ + wg] = f2b(v);
      }
}

// ---------------------------------------------------------------------------
// K3: depthwise 8x8 conv + BN (NCHW in/out, unchanged).
// ---------------------------------------------------------------------------
__global__ __launch_bounds__(256) void k_dwbn(
    const u16* __restrict__ out1, const float* __restrict__ wdw,
    const float* __restrict__ gam, const float* __restrict__ bet,
    const float* __restrict__ mea, const float* __restrict__ var,
    u16* __restrict__ bno)
{
  __shared__ u16 tile[23][264];
  const int tid = threadIdx.x, nb = blockIdx.x;
  const int c = nb & 255, ht = (nb >> 8) & 15, b = nb >> 12;
  const int h0 = ht * 16;

  for (int e = tid; e < 23 * 264; e += 256) {
    const int tr = e / 264, tc = e % 264;
    const int r = h0 - 3 + tr;
    const int cg = tc - 3;
    u16 v = 0;
    if (r >= 0 && r <= 256 && cg >= 0 && cg <= 256) {
      const int rr = (r == 256) ? 254 : r;
      const int cgm = (cg == 256) ? 254 : cg;
      v = out1[(((size_t)(b * C_ + c)) * H_ + rr) * W_ + cgm];
    }
    tile[tr][tc] = v;
  }
  float wk[64];
#pragma unroll
  for (int k2 = 0; k2 < 64; ++k2) wk[k2] = wdw[c * 64 + k2];
  const float scl = gam[c] / sqrtf(var[c] + 1e-5f);
  const float shf = bet[c] - mea[c] * scl;
  __syncthreads();

  const int wg = tid & 31, hg = tid >> 5;
  const int w0 = wg * 8;
#pragma unroll
  for (int k = 0; k < 2; ++k) {
    const int hl = hg * 2 + k;
    float a[8];
#pragma unroll
    for (int s = 0; s < 8; ++s) a[s] = 0.f;
#pragma unroll
    for (int i = 0; i < 8; ++i) {
      const uint4 va = *(const uint4*)&tile[hl + i][w0];
      const uint4 vb = *(const uint4*)&tile[hl + i][w0 + 8];
      float f[16];
      f[0] = b2f_lo(va.x);  f[1] = b2f_hi(va.x);  f[2] = b2f_lo(va.y);  f[3] = b2f_hi(va.y);
      f[4] = b2f_lo(va.z);  f[5] = b2f_hi(va.z);  f[6] = b2f_lo(va.w);  f[7] = b2f_hi(va.w);
      f[8] = b2f_lo(vb.x);  f[9] = b2f_hi(vb.x);  f[10] = b2f_lo(vb.y); f[11] = b2f_hi(vb.y);
      f[12] = b2f_lo(vb.z); f[13] = b2f_hi(vb.z); f[14] = b2f_lo(vb.w); f[15] = b2f_hi(vb.w);
#pragma unroll
      for (int j = 0; j < 8; ++j) {
        const float wv = wk[i * 8 + j];
#pragma unroll
        for (int s = 0; s < 8; ++s) a[s] += f[s + j] * wv;
      }
    }
    uint4 uv;
    uv.x = pack2(a[0] * scl + shf, a[1] * scl + shf);
    uv.y = pack2(a[2] * scl + shf, a[3] * scl + shf);
    uv.z = pack2(a[4] * scl + shf, a[5] * scl + shf);
    uv.w = pack2(a[6] * scl + shf, a[7] * scl + shf);
    *(uint4*)&bno[(((size_t)(b * C_ + c)) * H_ + h0 + hl) * W_ + w0] = uv;
  }
}

// ---------------------------------------------------------------------------
// K4: 1x1 projection (unchanged). Output FLOAT32.
// ---------------------------------------------------------------------------
__global__ __launch_bounds__(256) void k_proj(
    const u16* __restrict__ bno, const float* __restrict__ wp, float* __restrict__ out)
{
  __shared__ u16 bn[256][72];
  __shared__ u16 wpT[32][264];
  const int tid = threadIdx.x, nb = blockIdx.x;
  const int wtile = nb & 3, h = (nb >> 2) & 255, b = nb >> 10;
  const int w0 = wtile * 64;
  const int og = tid >> 3, pg = tid & 7;

  for (int k = 0; k < 8; ++k) {
    const int e = tid + k * 256;
    const int cc2 = e >> 3, seg = e & 7;
    *(uint4*)&bn[cc2][seg * 8] =
        *(const uint4*)&bno[(((size_t)(b * C_ + cc2)) * H_ + h) * W_ + w0 + seg * 8];
  }
  float acc[8][8];
#pragma unroll
  for (int a = 0; a < 8; ++a)
#pragma unroll
    for (int s = 0; s < 8; ++s) acc[a][s] = 0.f;

  for (int cb = 0; cb < 8; ++cb) {
    const int c0 = cb * 32;
    __syncthreads();
#pragma unroll
    for (int k = 0; k < 8; ++k) {
      const int e = tid + k * 256;
      const int o = e >> 3, g = e & 7;
      const float4 wv = *(const float4*)&wp[(size_t)o * 256 + c0 + g * 4];
      wpT[g * 4 + 0][o] = f2b(wv.x);
      wpT[g * 4 + 1][o] = f2b(wv.y);
      wpT[g * 4 + 2][o] = f2b(wv.z);
      wpT[g * 4 + 3][o] = f2b(wv.w);
    }
    __syncthreads();
    for (int cc = 0; cc < 32; ++cc) {
      const uint4 bv = *(const uint4*)&bn[c0 + cc][pg * 8];
      float bf[8];
      bf[0] = b2f_lo(bv.x); bf[1] = b2f_hi(bv.x); bf[2] = b2f_lo(bv.y); bf[3] = b2f_hi(bv.y);
      bf[4] = b2f_lo(bv.z); bf[5] = b2f_hi(bv.z); bf[6] = b2f_lo(bv.w); bf[7] = b2f_hi(bv.w);
      const uint4 wv = *(const uint4*)&wpT[cc][og * 8];
      float wf[8];
      wf[0] = b2f_lo(wv.x); wf[1] = b2f_hi(wv.x); wf[2] = b2f_lo(wv.y); wf[3] = b2f_hi(wv.y);
      wf[4] = b2f_lo(wv.z); wf[5] = b2f_hi(wv.z); wf[6] = b2f_lo(wv.w); wf[7] = b2f_hi(wv.w);
#pragma unroll
      for (int a = 0; a < 8; ++a)
#pragma unroll
        for (int s = 0; s < 8; ++s) acc[a][s] += wf[a] * bf[s];
    }
  }
#pragma unroll
  for (int a = 0; a < 8; ++a) {
    const int o = og * 8 + a;
    float* op = out + (((size_t)(b * C_ + o)) * H_ + h) * W_ + w0 + pg * 8;
    float4 v0; v0.x = acc[a][0]; v0.y = acc[a][1]; v0.z = acc[a][2]; v0.w = acc[a][3];
    float4 v1; v1.x = acc[a][4]; v1.y = acc[a][5]; v1.z = acc[a][6]; v1.w = acc[a][7];
    *(float4*)op = v0;
    *(float4*)(op + 4) = v1;
  }
}

// ---------------------------------------------------------------------------
extern "C" void kernel_launch(void* const* d_in, const int* in_sizes, int n_in,
                              void* d_out, int out_size, void* d_ws, size_t ws_size,
                              hipStream_t stream)
{
  const float* x     = (const float*)d_in[0];
  const float* wqkv  = (const float*)d_in[1];
  const float* rel   = (const float*)d_in[2];
  const float* wax   = (const float*)d_in[3];
  const float* bax   = (const float*)d_in[4];
  const float* way   = (const float*)d_in[5];
  const float* bay   = (const float*)d_in[6];
  const float* wdw   = (const float*)d_in[7];
  const float* gam   = (const float*)d_in[8];
  const float* bet   = (const float*)d_in[9];
  const float* mea   = (const float*)d_in[10];
  const float* var   = (const float*)d_in[11];
  const float* wproj = (const float*)d_in[12];
  float* out = (float*)d_out;

  const size_t N = (size_t)B_ * C_ * H_ * W_;
  u16* oNHWC  = (u16*)d_out;        // bf16 o, NHWC (first half of f32 out)
  u16* out1b  = (u16*)d_out + N;    // bf16 out1, NCHW (second half)
  u16* wtbuf  = (u16*)d_ws;         // bf16 WT [2][8][256][256] (2 MB)
  u16* bnbuf  = (u16*)d_ws;         // bf16 bn, NCHW (reuses WT region after K2)

  hipLaunchKernelGGL(k_wt,     dim3(256),  dim3(256), 0, stream, wax, way, wtbuf);
  hipLaunchKernelGGL(k_attn,   dim3(2048), dim3(256), 0, stream, x, wqkv, rel, oNHWC);
  hipLaunchKernelGGL(k_conv2m, dim3(2048), dim3(256), 0, stream, oNHWC, wtbuf, bax, bay, out1b);
  hipLaunchKernelGGL(k_dwbn,   dim3(8192), dim3(256), 0, stream, out1b, wdw, gam, bet, mea, var, bnbuf);
  hipLaunchKernelGGL(k_proj,   dim3(2048), dim3(256), 0, stream, bnbuf, wproj, out);
}